// Round 4
// baseline (113.635 us; speedup 1.0000x reference)
//
#include <hip/hip_runtime.h>
#include <hip/hip_bf16.h>

#define NPATCH 196

// Basis-change tile entries: per-wire 2x2 outer-product expressed in the
// (1, cos a, sin a) basis.  t(0,0)=(1+c)/2 ; t(1,1)=(1-c)/2 ; t(0,1)=t(1,0)=s/2
__device__ __forceinline__ float Tval(int bi, int bj, int al) {
  if (bi != bj) return (al == 2) ? 0.5f : 0.0f;
  if (al == 2) return 0.0f;
  if (al == 0) return 0.5f;
  return bi ? -0.5f : 0.5f;
}

// ---- setup: one block. Computes C[(a*9+q)*4+w] so that
//   feat_w(patch) = sum_{a,q} C[(a*9+q)*4+w] * m01[a] * m23[q]
// where m01/m23 are (1,cos,sin) products of the patch's full angles.
__global__ __launch_bounds__(256) void quanv_setup(const float* __restrict__ P,
                                                   float* __restrict__ C) {
  __shared__ float Vr[16][16];  // [row k][col i]
  __shared__ float Vi[16][16];
  __shared__ float A[4][16][16];  // un-doubled, full matrix (symmetric)
  const int tid = threadIdx.x;

  if (tid < 16) {  // simulate column `tid` of V (wire 0 = MSB, bit 3)
    float sr[16], si[16];
#pragma unroll
    for (int i = 0; i < 16; ++i) { sr[i] = (i == tid) ? 1.0f : 0.0f; si[i] = 0.0f; }
#pragma unroll
    for (int d = 0; d < 2; ++d) {
#pragma unroll
      for (int w = 0; w < 4; ++w) {
        const int m = 8 >> w;
        float th, c, s;
        th = P[(d * 4 + w) * 3 + 0];  // RX
        c = cosf(0.5f * th); s = sinf(0.5f * th);
#pragma unroll
        for (int i = 0; i < 16; ++i) if (!(i & m)) {
          const int j = i | m;
          const float r0 = sr[i], i0 = si[i], r1 = sr[j], i1 = si[j];
          sr[i] = c * r0 + s * i1; si[i] = c * i0 - s * r1;
          sr[j] = c * r1 + s * i0; si[j] = c * i1 - s * r0;
        }
        th = P[(d * 4 + w) * 3 + 1];  // RY
        c = cosf(0.5f * th); s = sinf(0.5f * th);
#pragma unroll
        for (int i = 0; i < 16; ++i) if (!(i & m)) {
          const int j = i | m;
          const float r0 = sr[i], i0 = si[i], r1 = sr[j], i1 = si[j];
          sr[i] = c * r0 - s * r1; si[i] = c * i0 - s * i1;
          sr[j] = s * r0 + c * r1; si[j] = s * i0 + c * i1;
        }
        th = P[(d * 4 + w) * 3 + 2];  // RZ
        c = cosf(0.5f * th); s = sinf(0.5f * th);
#pragma unroll
        for (int i = 0; i < 16; ++i) if (!(i & m)) {
          const int j = i | m;
          const float r0 = sr[i], i0 = si[i], r1 = sr[j], i1 = si[j];
          sr[i] = c * r0 + s * i0; si[i] = c * i0 - s * r0;
          sr[j] = c * r1 - s * i1; si[j] = c * i1 + s * r1;
        }
      }
#pragma unroll
      for (int g = 0; g < 4; ++g) {  // CNOT ring
        const int mc = 8 >> g, mt = 8 >> ((g + 1) & 3);
#pragma unroll
        for (int i = 0; i < 16; ++i) if ((i & mc) && !(i & mt)) {
          const int j = i | mt;
          float t;
          t = sr[i]; sr[i] = sr[j]; sr[j] = t;
          t = si[i]; si[i] = si[j]; si[j] = t;
        }
      }
    }
#pragma unroll
    for (int k = 0; k < 16; ++k) { Vr[k][tid] = sr[k]; Vi[k][tid] = si[k]; }
  }
  __syncthreads();

  {  // A_w[i][j] = sum_k z_w(k) * Re(conj(V[k][i]) V[k][j])
    const int i = tid >> 4, j = tid & 15;
    float s0 = 0, s1 = 0, s2 = 0, s3 = 0;
#pragma unroll
    for (int k = 0; k < 16; ++k) {
      const float pr = Vr[k][i] * Vr[k][j] + Vi[k][i] * Vi[k][j];
      s0 += (k & 8) ? -pr : pr;
      s1 += (k & 4) ? -pr : pr;
      s2 += (k & 2) ? -pr : pr;
      s3 += (k & 1) ? -pr : pr;
    }
    A[0][i][j] = s0; A[1][i][j] = s1; A[2][i][j] = s2; A[3][i][j] = s3;
  }
  __syncthreads();

  for (int idx = tid; idx < 324; idx += 256) {
    const int w = idx & 3;
    const int pidx = idx >> 2;
    const int a = pidx / 9, q = pidx % 9;
    const int a0 = a / 3, a1 = a % 3, a2 = q / 3, a3 = q % 3;
    float s = 0.0f;
    for (int i = 0; i < 16; ++i)
      for (int j = 0; j < 16; ++j) {
        float t = A[w][i][j];
        t *= Tval((i >> 3) & 1, (j >> 3) & 1, a0);
        t *= Tval((i >> 2) & 1, (j >> 2) & 1, a1);
        t *= Tval((i >> 1) & 1, (j >> 1) & 1, a2);
        t *= Tval(i & 1, j & 1, a3);
        s += t;
      }
    C[idx] = s;
  }
}

// ---- main: one block per image, 256 threads (196 patch threads).
__global__ __launch_bounds__(256) void quanv_main(const float* __restrict__ x,
                                                  const float* __restrict__ W,
                                                  const float* __restrict__ bias,
                                                  const float* __restrict__ C,
                                                  float* __restrict__ out) {
  __shared__ float wred[4][10];
  __shared__ float logits[10];
  __shared__ float snorm;
  const int tid = threadIdx.x;
  const int b = blockIdx.x;

  float lg[10];
#pragma unroll
  for (int k = 0; k < 10; ++k) lg[k] = 0.0f;

  if (tid < NPATCH) {
    const int pi = tid / 14, pj = tid - pi * 14;
    const float* px = x + b * 784 + pi * 56 + pj * 2;
    const float2 r0 = *reinterpret_cast<const float2*>(px);
    const float2 r1 = *reinterpret_cast<const float2*>(px + 28);
    float c0, s0, c1, s1, c2, s2, c3, s3;
    __sincosf(r0.x, &s0, &c0);
    __sincosf(r0.y, &s1, &c1);
    __sincosf(r1.x, &s2, &c2);
    __sincosf(r1.y, &s3, &c3);
    float m01[9], m23[9];
    m01[0] = 1.0f; m01[1] = c1;      m01[2] = s1;
    m01[3] = c0;   m01[4] = c0 * c1; m01[5] = c0 * s1;
    m01[6] = s0;   m01[7] = s0 * c1; m01[8] = s0 * s1;
    m23[0] = 1.0f; m23[1] = c3;      m23[2] = s3;
    m23[3] = c2;   m23[4] = c2 * c3; m23[5] = c2 * s3;
    m23[6] = s2;   m23[7] = s2 * c3; m23[8] = s2 * s3;

    float f0 = 0, f1 = 0, f2 = 0, f3 = 0;
    const float4* C4 = reinterpret_cast<const float4*>(C);
#pragma unroll
    for (int a = 0; a < 9; ++a) {
#pragma unroll
      for (int q = 0; q < 9; ++q) {
        const float pr = m01[a] * m23[q];       // wave-uniform C address below
        const float4 cc = C4[a * 9 + q];
        f0 += cc.x * pr; f1 += cc.y * pr; f2 += cc.z * pr; f3 += cc.w * pr;
      }
    }
    const float* Wp = W + tid * 4;  // feature index = tid*4 + w
#pragma unroll
    for (int k = 0; k < 10; ++k) {
      const float4 wv = *reinterpret_cast<const float4*>(Wp + k * 784);
      lg[k] = f0 * wv.x + f1 * wv.y + f2 * wv.z + f3 * wv.w;
    }
  }

  // wave-level reduction (64 lanes), then 4-wave LDS tail
#pragma unroll
  for (int k = 0; k < 10; ++k) {
    float v = lg[k];
    v += __shfl_xor(v, 32);
    v += __shfl_xor(v, 16);
    v += __shfl_xor(v, 8);
    v += __shfl_xor(v, 4);
    v += __shfl_xor(v, 2);
    v += __shfl_xor(v, 1);
    lg[k] = v;
  }
  const int lane = tid & 63, wid = tid >> 6;
  if (lane == 0) {
#pragma unroll
    for (int k = 0; k < 10; ++k) wred[wid][k] = lg[k];
  }
  __syncthreads();
  if (tid < 10)
    logits[tid] = wred[0][tid] + wred[1][tid] + wred[2][tid] + wred[3][tid] + bias[tid];
  __syncthreads();
  if (tid == 0) {
    float m = logits[0];
#pragma unroll
    for (int k = 1; k < 10; ++k) m = fmaxf(m, logits[k]);
    float se = 0;
#pragma unroll
    for (int k = 0; k < 10; ++k) se += expf(logits[k] - m);
    snorm = m + logf(se);
  }
  __syncthreads();
  if (tid < 10) out[b * 10 + tid] = logits[tid] - snorm;
}

extern "C" void kernel_launch(void* const* d_in, const int* in_sizes, int n_in,
                              void* d_out, int out_size, void* d_ws, size_t ws_size,
                              hipStream_t stream) {
  const float* x = (const float*)d_in[0];     // (B,1,28,28) f32
  const float* P = (const float*)d_in[1];     // (2,4,3) f32
  const float* W = (const float*)d_in[2];     // (10,784) f32
  const float* bias = (const float*)d_in[3];  // (10,) f32
  float* out = (float*)d_out;                 // (B,10) f32
  float* C = (float*)d_ws;                    // 324 floats scratch
  const int B = out_size / 10;

  quanv_setup<<<1, 256, 0, stream>>>(P, C);
  quanv_main<<<B, 256, 0, stream>>>(x, W, bias, C, out);
}

// Round 5
// 27.597 us; speedup vs baseline: 4.1176x; 4.1176x over previous
//
#include <hip/hip_runtime.h>
#include <hip/hip_bf16.h>

#define NPATCH 196

// ---- setup: ONE block, 256 threads, fully parallel.
// Computes C[(a*9+q)*4+w] so that
//   feat_w(patch) = sum_{a,q} C[(a*9+q)*4+w] * m01[a] * m23[q]
// where m01/m23 are (1,cos,sin) products of the patch's full angles,
//   a = 3*alpha0 + alpha1, q = 3*alpha2 + alpha3.
__global__ __launch_bounds__(256) void quanv_setup(const float* __restrict__ P,
                                                   float* __restrict__ C) {
  __shared__ float Sr[2][16][16], Si[2][16][16];  // ping-pong state matrix [buf][row k][col i]
  __shared__ float gc[24], gs[24];
  __shared__ float A[4][16][16];            // A_w[i][j]
  __shared__ float B0[4][3][8][8];          // wire0 contracted
  __shared__ float B1[4][3][3][4][4];       // wire1 contracted
  __shared__ float B2[4][3][3][3][2][2];    // wire2 contracted
  const int tid = threadIdx.x;
  const int row = tid >> 4, col = tid & 15;

  if (tid < 24) {  // gate angle sin/cos in parallel; P laid out [(d*4+w)*3+g]
    float s, c;
    __sincosf(0.5f * P[tid], &s, &c);
    gc[tid] = c; gs[tid] = s;
  }
  Sr[0][row][col] = (row == col) ? 1.0f : 0.0f;  // S = I
  Si[0][row][col] = 0.0f;
  __syncthreads();

  int cur = 0;
  // ---- V simulation: each thread owns matrix entry (row,col). wire w = bit (3-w).
  for (int d = 0; d < 2; ++d) {
    for (int w = 0; w < 4; ++w) {
      const int m = 8 >> w;
      const int par = row ^ m;
      for (int g = 0; g < 3; ++g) {
        const int gi = (d * 4 + w) * 3 + g;
        const float c = gc[gi], s = gs[gi];
        const float r0 = Sr[cur][row][col], i0 = Si[cur][row][col];
        const float r1 = Sr[cur][par][col], i1 = Si[cur][par][col];
        float rn, in_;
        if (g == 0) {            // RX: v' = c*self - i*s*partner (symmetric)
          rn = c * r0 + s * i1;
          in_ = c * i0 - s * r1;
        } else if (g == 1) {     // RY: partner coeff -s (bit0) / +s (bit1)
          const float sg = (row & m) ? s : -s;
          rn = c * r0 + sg * r1;
          in_ = c * i0 + sg * i1;
        } else {                 // RZ: *(c -+ i s) by bit
          const float sg = (row & m) ? s : -s;
          rn = c * r0 - sg * i0;
          in_ = c * i0 + sg * r0;
        }
        Sr[cur ^ 1][row][col] = rn;
        Si[cur ^ 1][row][col] = in_;
        cur ^= 1;
        __syncthreads();
      }
    }
    // CNOT ring (0,1),(1,2),(2,3),(3,0) as one permutation:
    // new[k] = old[c01(c12(c23(c30(k))))], each c is self-inverse.
    int k = row;
    k ^= (k & 1) ? 8 : 0;  // c30: mc=1, mt=8
    k ^= (k & 2) ? 1 : 0;  // c23: mc=2, mt=1
    k ^= (k & 4) ? 2 : 0;  // c12: mc=4, mt=2
    k ^= (k & 8) ? 4 : 0;  // c01: mc=8, mt=4
    const float pr = Sr[cur][k][col], pi = Si[cur][k][col];
    Sr[cur ^ 1][row][col] = pr;
    Si[cur ^ 1][row][col] = pi;
    cur ^= 1;
    __syncthreads();
  }

  // ---- A_w[i][j] = sum_k z_w(k) * Re(conj(V[k][i]) V[k][j])   (V real*conj: psi real)
  {
    const int i = row, j = col;
    float s0 = 0, s1 = 0, s2 = 0, s3 = 0;
#pragma unroll
    for (int k = 0; k < 16; ++k) {
      const float pr = Sr[cur][k][i] * Sr[cur][k][j] + Si[cur][k][i] * Si[cur][k][j];
      s0 += (k & 8) ? -pr : pr;
      s1 += (k & 4) ? -pr : pr;
      s2 += (k & 2) ? -pr : pr;
      s3 += (k & 1) ? -pr : pr;
    }
    A[0][i][j] = s0; A[1][i][j] = s1; A[2][i][j] = s2; A[3][i][j] = s3;
  }
  __syncthreads();

  // ---- wire-factorized basis transform: per wire, alpha combos are
  //   a=0: 0.5*(X00+X11) ; a=1: 0.5*(X00-X11) ; a=2: 0.5*(X01+X10)
  {  // wire 0 (bit 3): A -> B0 ; 4*64 = 256 threads, 3 outputs each
    const int w = tid >> 6, ip = (tid >> 3) & 7, jp = tid & 7;
    const float a00 = A[w][ip][jp],     a11 = A[w][ip + 8][jp + 8];
    const float a01 = A[w][ip][jp + 8], a10 = A[w][ip + 8][jp];
    B0[w][0][ip][jp] = 0.5f * (a00 + a11);
    B0[w][1][ip][jp] = 0.5f * (a00 - a11);
    B0[w][2][ip][jp] = 0.5f * (a01 + a10);
  }
  __syncthreads();
  if (tid < 192) {  // wire 1 (bit 2): B0 -> B1 ; 4*3*16 = 192
    const int w = tid / 48, a0 = (tid / 16) % 3, ii = (tid >> 2) & 3, jj = tid & 3;
    const float a00 = B0[w][a0][ii][jj],     a11 = B0[w][a0][ii + 4][jj + 4];
    const float a01 = B0[w][a0][ii][jj + 4], a10 = B0[w][a0][ii + 4][jj];
    B1[w][a0][0][ii][jj] = 0.5f * (a00 + a11);
    B1[w][a0][1][ii][jj] = 0.5f * (a00 - a11);
    B1[w][a0][2][ii][jj] = 0.5f * (a01 + a10);
  }
  __syncthreads();
  if (tid < 144) {  // wire 2 (bit 1): B1 -> B2 ; 4*3*3*4 = 144
    const int w = tid / 36, a0 = (tid / 12) % 3, a1 = (tid / 4) % 3;
    const int i3 = (tid >> 1) & 1, j3 = tid & 1;
    const float a00 = B1[w][a0][a1][i3][j3],     a11 = B1[w][a0][a1][i3 + 2][j3 + 2];
    const float a01 = B1[w][a0][a1][i3][j3 + 2], a10 = B1[w][a0][a1][i3 + 2][j3];
    B2[w][a0][a1][0][i3][j3] = 0.5f * (a00 + a11);
    B2[w][a0][a1][1][i3][j3] = 0.5f * (a00 - a11);
    B2[w][a0][a1][2][i3][j3] = 0.5f * (a01 + a10);
  }
  __syncthreads();
  if (tid < 108) {  // wire 3 (bit 0): B2 -> C ; 4*27 = 108
    const int w = tid / 27, r = tid % 27;
    const int a0 = r / 9, a1 = (r / 3) % 3, a2 = r % 3;
    const float a00 = B2[w][a0][a1][a2][0][0], a11 = B2[w][a0][a1][a2][1][1];
    const float a01 = B2[w][a0][a1][a2][0][1], a10 = B2[w][a0][a1][a2][1][0];
    const int base = (3 * a0 + a1) * 9 + 3 * a2;
    C[(base + 0) * 4 + w] = 0.5f * (a00 + a11);
    C[(base + 1) * 4 + w] = 0.5f * (a00 - a11);
    C[(base + 2) * 4 + w] = 0.5f * (a01 + a10);
  }
}

// ---- main: one block per image, 256 threads (196 patch threads). UNCHANGED from round 4.
__global__ __launch_bounds__(256) void quanv_main(const float* __restrict__ x,
                                                  const float* __restrict__ W,
                                                  const float* __restrict__ bias,
                                                  const float* __restrict__ C,
                                                  float* __restrict__ out) {
  __shared__ float wred[4][10];
  __shared__ float logits[10];
  __shared__ float snorm;
  const int tid = threadIdx.x;
  const int b = blockIdx.x;

  float lg[10];
#pragma unroll
  for (int k = 0; k < 10; ++k) lg[k] = 0.0f;

  if (tid < NPATCH) {
    const int pi = tid / 14, pj = tid - pi * 14;
    const float* px = x + b * 784 + pi * 56 + pj * 2;
    const float2 r0 = *reinterpret_cast<const float2*>(px);
    const float2 r1 = *reinterpret_cast<const float2*>(px + 28);
    float c0, s0, c1, s1, c2, s2, c3, s3;
    __sincosf(r0.x, &s0, &c0);
    __sincosf(r0.y, &s1, &c1);
    __sincosf(r1.x, &s2, &c2);
    __sincosf(r1.y, &s3, &c3);
    float m01[9], m23[9];
    m01[0] = 1.0f; m01[1] = c1;      m01[2] = s1;
    m01[3] = c0;   m01[4] = c0 * c1; m01[5] = c0 * s1;
    m01[6] = s0;   m01[7] = s0 * c1; m01[8] = s0 * s1;
    m23[0] = 1.0f; m23[1] = c3;      m23[2] = s3;
    m23[3] = c2;   m23[4] = c2 * c3; m23[5] = c2 * s3;
    m23[6] = s2;   m23[7] = s2 * c3; m23[8] = s2 * s3;

    float f0 = 0, f1 = 0, f2 = 0, f3 = 0;
    const float4* C4 = reinterpret_cast<const float4*>(C);
#pragma unroll
    for (int a = 0; a < 9; ++a) {
#pragma unroll
      for (int q = 0; q < 9; ++q) {
        const float pr = m01[a] * m23[q];
        const float4 cc = C4[a * 9 + q];
        f0 += cc.x * pr; f1 += cc.y * pr; f2 += cc.z * pr; f3 += cc.w * pr;
      }
    }
    const float* Wp = W + tid * 4;  // feature index = tid*4 + w
#pragma unroll
    for (int k = 0; k < 10; ++k) {
      const float4 wv = *reinterpret_cast<const float4*>(Wp + k * 784);
      lg[k] = f0 * wv.x + f1 * wv.y + f2 * wv.z + f3 * wv.w;
    }
  }

  // wave-level reduction, then 4-wave LDS tail
#pragma unroll
  for (int k = 0; k < 10; ++k) {
    float v = lg[k];
    v += __shfl_xor(v, 32);
    v += __shfl_xor(v, 16);
    v += __shfl_xor(v, 8);
    v += __shfl_xor(v, 4);
    v += __shfl_xor(v, 2);
    v += __shfl_xor(v, 1);
    lg[k] = v;
  }
  const int lane = tid & 63, wid = tid >> 6;
  if (lane == 0) {
#pragma unroll
    for (int k = 0; k < 10; ++k) wred[wid][k] = lg[k];
  }
  __syncthreads();
  if (tid < 10)
    logits[tid] = wred[0][tid] + wred[1][tid] + wred[2][tid] + wred[3][tid] + bias[tid];
  __syncthreads();
  if (tid == 0) {
    float m = logits[0];
#pragma unroll
    for (int k = 1; k < 10; ++k) m = fmaxf(m, logits[k]);
    float se = 0;
#pragma unroll
    for (int k = 0; k < 10; ++k) se += expf(logits[k] - m);
    snorm = m + logf(se);
  }
  __syncthreads();
  if (tid < 10) out[b * 10 + tid] = logits[tid] - snorm;
}

extern "C" void kernel_launch(void* const* d_in, const int* in_sizes, int n_in,
                              void* d_out, int out_size, void* d_ws, size_t ws_size,
                              hipStream_t stream) {
  const float* x = (const float*)d_in[0];     // (B,1,28,28) f32
  const float* P = (const float*)d_in[1];     // (2,4,3) f32
  const float* W = (const float*)d_in[2];     // (10,784) f32
  const float* bias = (const float*)d_in[3];  // (10,) f32
  float* out = (float*)d_out;                 // (B,10) f32
  float* C = (float*)d_ws;                    // 324 floats scratch
  const int B = out_size / 10;

  quanv_setup<<<1, 256, 0, stream>>>(P, C);
  quanv_main<<<B, 256, 0, stream>>>(x, W, bias, C, out);
}

// Round 6
// 24.433 us; speedup vs baseline: 4.6508x; 1.1295x over previous
//
#include <hip/hip_runtime.h>
#include <hip/hip_bf16.h>

#define NPATCH 196

typedef float f2 __attribute__((ext_vector_type(2)));

// ---- setup: ONE block, 256 threads.
// Computes C[(a*9+q)*4+w] so that feat_w = sum_{a,q} C[(a*9+q)*4+w]*m01[a]*m23[q],
// a = 3*alpha0+alpha1 (wires 0,1), q = 3*alpha2+alpha3 (wires 2,3),
// alpha: 0->1, 1->cos(angle), 2->sin(angle).
__global__ __launch_bounds__(256) void quanv_setup(const float* __restrict__ P,
                                                   float* __restrict__ C) {
  __shared__ float gc[24], gs[24];
  __shared__ float Ur[8][2][2], Ui[8][2][2];  // merged RZ*RY*RX per (d,w)
  __shared__ float Sr[2][16][16], Si[2][16][16];
  __shared__ float A[4][16][16];
  __shared__ float B0[4][3][8][8];
  __shared__ float B1[4][3][3][4][4];
  __shared__ float B2[4][3][3][3][2][2];
  const int tid = threadIdx.x;
  const int row = tid >> 4, col = tid & 15;

  if (tid < 24) {  // P laid out [(d*4+w)*3+g]; |theta/2| small -> __sincosf fine
    float s, c;
    __sincosf(0.5f * P[tid], &s, &c);
    gc[tid] = c; gs[tid] = s;
  }
  Sr[0][row][col] = (row == col) ? 1.0f : 0.0f;
  Si[0][row][col] = 0.0f;
  __syncthreads();

  if (tid < 8) {  // U = RZ(t3)*RY(t2)*RX(t1), 2x2 complex
    const int base = tid * 3;
    const float c1 = gc[base], s1 = gs[base];
    const float c2 = gc[base + 1], s2 = gs[base + 1];
    const float c3 = gc[base + 2], s3 = gs[base + 2];
    // M1 = RY*RX
    const float m00r = c2 * c1, m00i = s2 * s1;
    const float m01r = -s2 * c1, m01i = -c2 * s1;
    const float m10r = s2 * c1, m10i = -c2 * s1;
    const float m11r = c2 * c1, m11i = -s2 * s1;
    // row0 *= (c3 - i s3); row1 *= (c3 + i s3)
    Ur[tid][0][0] = c3 * m00r + s3 * m00i;  Ui[tid][0][0] = c3 * m00i - s3 * m00r;
    Ur[tid][0][1] = c3 * m01r + s3 * m01i;  Ui[tid][0][1] = c3 * m01i - s3 * m01r;
    Ur[tid][1][0] = c3 * m10r - s3 * m10i;  Ui[tid][1][0] = c3 * m10i + s3 * m10r;
    Ur[tid][1][1] = c3 * m11r - s3 * m11i;  Ui[tid][1][1] = c3 * m11i + s3 * m11r;
  }
  __syncthreads();

  int cur = 0;
  for (int d = 0; d < 2; ++d) {
    for (int w = 0; w < 4; ++w) {
      const int gi = d * 4 + w;
      const int m = 8 >> w;
      const int bit = (row & m) ? 1 : 0;
      const int par = row ^ m;
      const int r0 = bit ? par : row, r1 = bit ? row : par;  // (v0,v1) of the 2x2 subspace
      const float a_r = Sr[cur][r0][col], a_i = Si[cur][r0][col];
      const float b_r = Sr[cur][r1][col], b_i = Si[cur][r1][col];
      const float u0r = Ur[gi][bit][0], u0i = Ui[gi][bit][0];
      const float u1r = Ur[gi][bit][1], u1i = Ui[gi][bit][1];
      const float rn = u0r * a_r - u0i * a_i + u1r * b_r - u1i * b_i;
      const float in_ = u0r * a_i + u0i * a_r + u1r * b_i + u1i * b_r;
      Sr[cur ^ 1][row][col] = rn;
      Si[cur ^ 1][row][col] = in_;
      cur ^= 1;
      __syncthreads();
    }
    if (d == 0) {  // CNOT ring as one permutation: new[k] = old[chain(k)]
      int k = row;
      k ^= (k & 1) ? 8 : 0;
      k ^= (k & 2) ? 1 : 0;
      k ^= (k & 4) ? 2 : 0;
      k ^= (k & 8) ? 4 : 0;
      const float pr_ = Sr[cur][k][col], pi_ = Si[cur][k][col];
      Sr[cur ^ 1][row][col] = pr_;
      Si[cur ^ 1][row][col] = pi_;
      cur ^= 1;
      __syncthreads();
    }
  }

  // A_w[i][j] = sum_k z_w(k)*Re(conj(V[k][i])V[k][j]); final CNOT perm folded: V[k]=S[chain(k)]
  {
    const int i = row, j = col;
    float s0 = 0, s1 = 0, s2 = 0, s3 = 0;
#pragma unroll
    for (int k = 0; k < 16; ++k) {
      int gk = k;
      gk ^= (gk & 1) ? 8 : 0;
      gk ^= (gk & 2) ? 1 : 0;
      gk ^= (gk & 4) ? 2 : 0;
      gk ^= (gk & 8) ? 4 : 0;
      const float pr = Sr[cur][gk][i] * Sr[cur][gk][j] + Si[cur][gk][i] * Si[cur][gk][j];
      s0 += (k & 8) ? -pr : pr;
      s1 += (k & 4) ? -pr : pr;
      s2 += (k & 2) ? -pr : pr;
      s3 += (k & 1) ? -pr : pr;
    }
    A[0][i][j] = s0; A[1][i][j] = s1; A[2][i][j] = s2; A[3][i][j] = s3;
  }
  __syncthreads();

  // wire-factorized basis transform: a=0: .5(X00+X11); a=1: .5(X00-X11); a=2: .5(X01+X10)
  {  // wire 0 (bit 3): A -> B0
    const int w = tid >> 6, ip = (tid >> 3) & 7, jp = tid & 7;
    const float a00 = A[w][ip][jp],     a11 = A[w][ip + 8][jp + 8];
    const float a01 = A[w][ip][jp + 8], a10 = A[w][ip + 8][jp];
    B0[w][0][ip][jp] = 0.5f * (a00 + a11);
    B0[w][1][ip][jp] = 0.5f * (a00 - a11);
    B0[w][2][ip][jp] = 0.5f * (a01 + a10);
  }
  __syncthreads();
  if (tid < 192) {  // wire 1 (bit 2)
    const int w = tid / 48, a0 = (tid / 16) % 3, ii = (tid >> 2) & 3, jj = tid & 3;
    const float a00 = B0[w][a0][ii][jj],     a11 = B0[w][a0][ii + 4][jj + 4];
    const float a01 = B0[w][a0][ii][jj + 4], a10 = B0[w][a0][ii + 4][jj];
    B1[w][a0][0][ii][jj] = 0.5f * (a00 + a11);
    B1[w][a0][1][ii][jj] = 0.5f * (a00 - a11);
    B1[w][a0][2][ii][jj] = 0.5f * (a01 + a10);
  }
  __syncthreads();
  if (tid < 144) {  // wire 2 (bit 1)
    const int w = tid / 36, a0 = (tid / 12) % 3, a1 = (tid / 4) % 3;
    const int i3 = (tid >> 1) & 1, j3 = tid & 1;
    const float a00 = B1[w][a0][a1][i3][j3],     a11 = B1[w][a0][a1][i3 + 2][j3 + 2];
    const float a01 = B1[w][a0][a1][i3][j3 + 2], a10 = B1[w][a0][a1][i3 + 2][j3];
    B2[w][a0][a1][0][i3][j3] = 0.5f * (a00 + a11);
    B2[w][a0][a1][1][i3][j3] = 0.5f * (a00 - a11);
    B2[w][a0][a1][2][i3][j3] = 0.5f * (a01 + a10);
  }
  __syncthreads();
  if (tid < 108) {  // wire 3 (bit 0): B2 -> C
    const int w = tid / 27, r = tid % 27;
    const int a0 = r / 9, a1 = (r / 3) % 3, a2 = r % 3;
    const float a00 = B2[w][a0][a1][a2][0][0], a11 = B2[w][a0][a1][a2][1][1];
    const float a01 = B2[w][a0][a1][a2][0][1], a10 = B2[w][a0][a1][a2][1][0];
    const int base = (3 * a0 + a1) * 9 + 3 * a2;
    C[(base + 0) * 4 + w] = 0.5f * (a00 + a11);
    C[(base + 1) * 4 + w] = 0.5f * (a00 - a11);
    C[(base + 2) * 4 + w] = 0.5f * (a01 + a10);
  }
}

// ---- main: one block per image, 256 threads (196 patch threads).
// Packed-f32 contraction: f_w = m01^T M_w m23, (w0,w1)/(w2,w3) as float2 lanes.
__global__ __launch_bounds__(256) void quanv_main(const float* __restrict__ x,
                                                  const float* __restrict__ W,
                                                  const float* __restrict__ bias,
                                                  const float* __restrict__ C,
                                                  float* __restrict__ out) {
  __shared__ float red2[49][10];
  __shared__ float logits[10];
  __shared__ float snorm;
  const int tid = threadIdx.x;
  const int b = blockIdx.x;

  float lg[10];
#pragma unroll
  for (int k = 0; k < 10; ++k) lg[k] = 0.0f;

  if (tid < NPATCH) {
    const int pi = tid / 14, pj = tid - pi * 14;
    const float* px = x + b * 784 + pi * 56 + pj * 2;
    const float2 r0 = *reinterpret_cast<const float2*>(px);
    const float2 r1 = *reinterpret_cast<const float2*>(px + 28);
    float c0, s0, c1, s1, c2, s2, c3, s3;
    __sincosf(r0.x, &s0, &c0);
    __sincosf(r0.y, &s1, &c1);
    __sincosf(r1.x, &s2, &c2);
    __sincosf(r1.y, &s3, &c3);
    const float m01s[9] = {1.0f, c1, s1, c0, c0 * c1, c0 * s1, s0, s0 * c1, s0 * s1};
    const float m23s[9] = {1.0f, c3, s3, c2, c2 * c3, c2 * s3, s2, s2 * c3, s2 * s3};
    f2 m23b[9];
#pragma unroll
    for (int q = 0; q < 9; ++q) m23b[q] = (f2){m23s[q], m23s[q]};

    f2 f01 = {0.0f, 0.0f}, f23 = {0.0f, 0.0f};
    const f2* C2 = reinterpret_cast<const f2*>(C);
#pragma unroll
    for (int a = 0; a < 9; ++a) {
      f2 t01 = {0.0f, 0.0f}, t23 = {0.0f, 0.0f};
#pragma unroll
      for (int q = 0; q < 9; ++q) {
        const int idx = (a * 9 + q) * 2;
        t01 += C2[idx] * m23b[q];      // v_pk_fma_f32
        t23 += C2[idx + 1] * m23b[q];
      }
      f01 += t01 * m01s[a];
      f23 += t23 * m01s[a];
    }
    const float f0 = f01.x, f1 = f01.y, f2v = f23.x, f3 = f23.y;

    const float* Wp = W + tid * 4;  // feature index = tid*4 + w
#pragma unroll
    for (int k = 0; k < 10; ++k) {
      const float4 wv = *reinterpret_cast<const float4*>(Wp + k * 784);
      lg[k] = f0 * wv.x + f1 * wv.y + f2v * wv.z + f3 * wv.w;
    }
  }

  // 2-step butterfly -> 4-lane group sums; distribute LDS writes across the group
#pragma unroll
  for (int k = 0; k < 10; ++k) {
    lg[k] += __shfl_xor(lg[k], 1);
    lg[k] += __shfl_xor(lg[k], 2);
  }
  if (tid < NPATCH) {
    const int g = tid >> 2, sub = tid & 3;
#pragma unroll
    for (int k = 0; k < 10; ++k)
      if ((k & 3) == sub) red2[g][k] = lg[k];
  }
  __syncthreads();
  if (tid < 10) {
    float s = bias[tid];
    for (int g2 = 0; g2 < 49; ++g2) s += red2[g2][tid];
    logits[tid] = s;
  }
  __syncthreads();
  if (tid == 0) {
    float m = logits[0];
#pragma unroll
    for (int k = 1; k < 10; ++k) m = fmaxf(m, logits[k]);
    float se = 0;
#pragma unroll
    for (int k = 0; k < 10; ++k) se += expf(logits[k] - m);
    snorm = m + logf(se);
  }
  __syncthreads();
  if (tid < 10) out[b * 10 + tid] = logits[tid] - snorm;
}

extern "C" void kernel_launch(void* const* d_in, const int* in_sizes, int n_in,
                              void* d_out, int out_size, void* d_ws, size_t ws_size,
                              hipStream_t stream) {
  const float* x = (const float*)d_in[0];     // (B,1,28,28) f32
  const float* P = (const float*)d_in[1];     // (2,4,3) f32
  const float* W = (const float*)d_in[2];     // (10,784) f32
  const float* bias = (const float*)d_in[3];  // (10,) f32
  float* out = (float*)d_out;                 // (B,10) f32
  float* C = (float*)d_ws;                    // 324 floats scratch
  const int B = out_size / 10;

  quanv_setup<<<1, 256, 0, stream>>>(P, C);
  quanv_main<<<B, 256, 0, stream>>>(x, W, bias, C, out);
}